// Round 3
// baseline (462.815 us; speedup 1.0000x reference)
//
#include <hip/hip_runtime.h>
#include <hip/hip_bf16.h>
#include <stdint.h>

#define NDIM 3072
#define BATCHN 8192
#define KTOP 16.0f
#define NITER 50

typedef __attribute__((ext_vector_type(8))) short short8;
typedef __attribute__((ext_vector_type(4))) float floatx4;
typedef __attribute__((ext_vector_type(4))) unsigned short ushortx4;

__device__ inline unsigned short f2bf(float f) {
    __hip_bfloat16 h = __float2bfloat16(f);
    return *reinterpret_cast<unsigned short*>(&h);
}

// ---------------- K1: Dykstra soft-topk, reduced to scalar-D recursion ----------------
// s = x + q evolves as s += (k - sum(x))/n (uniform shift); x = clip(z + D).
// Single wave (64 lanes), 48 elements/lane in registers, butterfly reductions, no barriers.
__global__ void dykstra_kernel(const float* __restrict__ alpha, float* __restrict__ a_out) {
    const int lane = threadIdx.x;  // 64 threads
    float z[48];
    float sl = 0.f;
#pragma unroll
    for (int e = 0; e < 48; ++e) {
        z[e] = alpha[e * 64 + lane] / 0.01f;   // z = alpha / l, match reference's division
        sl += z[e];
    }
    float S = sl;
#pragma unroll
    for (int m = 1; m < 64; m <<= 1) S += __shfl_xor(S, m, 64);  // S_0 = sum(z)

    float D = 0.f;
    for (int it = 0; it < NITER; ++it) {
        D += (KTOP - S) / (float)NDIM;
        float s2 = 0.f;
#pragma unroll
        for (int e = 0; e < 48; ++e) {
            float v = z[e] + D;
            v = v < 0.f ? 0.f : (v > 1.f ? 1.f : v);
            s2 += v;
        }
        S = s2;
#pragma unroll
        for (int m = 1; m < 64; m <<= 1) S += __shfl_xor(S, m, 64);
    }
#pragma unroll
    for (int e = 0; e < 48; ++e) {
        float v = z[e] + D;
        v = v < 0.f ? 0.f : (v > 1.f ? 1.f : v);
        a_out[e * 64 + lane] = v;
    }
}

// ---------------- K2: build W[r,c] = a[(r-c)%n] * V[(r-c)%n, c] as bf16 ----------------
// 64x64 output tile per block; the needed V elements form a 127-row parallelogram,
// staged row-wise (coalesced 256B) into LDS.
__global__ __launch_bounds__(256) void build_w(const float* __restrict__ V,
                                               const float* __restrict__ a,
                                               unsigned short* __restrict__ W) {
    __shared__ float Vs[128][64];
    __shared__ float as_[128];
    const int tid = threadIdx.x;
    const int c0 = blockIdx.x * 64;
    const int r0 = blockIdx.y * 64;
    int ib = r0 - c0 - 63;
    ib %= NDIM; if (ib < 0) ib += NDIM;

    if (tid < 128) {
        int i = ib + tid; if (i >= NDIM) i -= NDIM;
        as_[tid] = a[i];
    }
#pragma unroll
    for (int it = 0; it < 32; ++it) {
        int idx = it * 256 + tid;
        int d = idx >> 6, cc = idx & 63;
        int i = ib + d; if (i >= NDIM) i -= NDIM;
        Vs[d][cc] = V[(size_t)i * NDIM + c0 + cc];
    }
    __syncthreads();

    const int cc = tid & 63;
    const int rrb = (tid >> 6) * 16;
#pragma unroll
    for (int p = 0; p < 16; ++p) {
        int rr = rrb + p;
        int d = rr - cc + 63;                       // in [0,126]
        float v = as_[d] * Vs[d][cc];
        W[(size_t)(r0 + rr) * NDIM + (c0 + cc)] = f2bf(v);
    }
}

// ---------------- K3: x f32 -> bf16 ----------------
__global__ void convert_x(const float* __restrict__ x, unsigned short* __restrict__ xb, int n) {
    int i = (blockIdx.x * blockDim.x + threadIdx.x) * 4;
    const int stride = gridDim.x * blockDim.x * 4;
    for (; i < n; i += stride) {
        floatx4 v = *(const floatx4*)(x + i);
        ushortx4 o;
        o[0] = f2bf(v[0]); o[1] = f2bf(v[1]); o[2] = f2bf(v[2]); o[3] = f2bf(v[3]);
        *(ushortx4*)(xb + i) = o;
    }
}

// ---------------- K4: bf16 GEMM, C[M,N] = A[M,K] * B[N,K]^T  (m97-style 128^2 tile) ----------------
#define BM 128
#define BN 128
#define BK 64

__global__ __launch_bounds__(256) void gemm_bt(const unsigned short* __restrict__ A,
                                               const unsigned short* __restrict__ B,
                                               float* __restrict__ C,
                                               int M, int N, int K, int ntiles_n) {
    __shared__ __align__(16) unsigned short As[BM * BK];
    __shared__ __align__(16) unsigned short Bs[BN * BK];

    // XCD-aware bijective swizzle (grid = 1536, divisible by 8)
    const int nwg = gridDim.x;
    const int cpx = nwg >> 3;
    const int bid = blockIdx.x;
    const int swz = (bid & 7) * cpx + (bid >> 3);
    const int tm = swz / ntiles_n, tn = swz % ntiles_n;
    const int m0 = tm * BM, n0 = tn * BN;

    const int tid = threadIdx.x;
    const int lane = tid & 63;
    const int wid = tid >> 6;       // 4 waves, 2x2
    const int wm = wid >> 1, wn = wid & 1;

    floatx4 acc[4][4];
#pragma unroll
    for (int i = 0; i < 4; ++i)
#pragma unroll
        for (int j = 0; j < 4; ++j) acc[i][j] = {0.f, 0.f, 0.f, 0.f};

    const unsigned short* Ab = A + (size_t)m0 * K;
    const unsigned short* Bb = B + (size_t)n0 * K;

    for (int kt = 0; kt < K; kt += BK) {
        __syncthreads();  // previous compute done before overwriting LDS
#pragma unroll
        for (int li = 0; li < 4; ++li) {
            int off = li * 4096 + tid * 16;     // byte offset in 16KB tile, 128B per row
            int row = off >> 7;
            int col = (off & 127) >> 1;         // bf16 elems
            const unsigned short* g = Ab + (size_t)row * K + kt + col;
            __builtin_amdgcn_global_load_lds(
                (const __attribute__((address_space(1))) unsigned int*)g,
                (__attribute__((address_space(3))) unsigned int*)((char*)As + off),
                16, 0, 0);
        }
#pragma unroll
        for (int li = 0; li < 4; ++li) {
            int off = li * 4096 + tid * 16;
            int row = off >> 7;
            int col = (off & 127) >> 1;
            const unsigned short* g = Bb + (size_t)row * K + kt + col;
            __builtin_amdgcn_global_load_lds(
                (const __attribute__((address_space(1))) unsigned int*)g,
                (__attribute__((address_space(3))) unsigned int*)((char*)Bs + off),
                16, 0, 0);
        }
        asm volatile("s_waitcnt vmcnt(0)" ::: "memory");
        __syncthreads();

#pragma unroll
        for (int ks = 0; ks < 2; ++ks) {
            short8 af[4], bf[4];
#pragma unroll
            for (int mi = 0; mi < 4; ++mi) {
                int r = wm * 64 + mi * 16 + (lane & 15);
                int c = ks * 32 + (lane >> 4) * 8;
                af[mi] = *(const short8*)&As[r * BK + c];
            }
#pragma unroll
            for (int ni = 0; ni < 4; ++ni) {
                int r = wn * 64 + ni * 16 + (lane & 15);
                int c = ks * 32 + (lane >> 4) * 8;
                bf[ni] = *(const short8*)&Bs[r * BK + c];
            }
#pragma unroll
            for (int mi = 0; mi < 4; ++mi)
#pragma unroll
                for (int ni = 0; ni < 4; ++ni)
                    acc[mi][ni] = __builtin_amdgcn_mfma_f32_16x16x32_bf16(af[mi], bf[ni], acc[mi][ni], 0, 0, 0);
        }
    }

    // epilogue: C/D layout col = lane&15, row = (lane>>4)*4 + reg  [m89-verified]
#pragma unroll
    for (int mi = 0; mi < 4; ++mi)
#pragma unroll
        for (int ni = 0; ni < 4; ++ni)
#pragma unroll
            for (int rg = 0; rg < 4; ++rg) {
                int rr = m0 + wm * 64 + mi * 16 + (lane >> 4) * 4 + rg;
                int cc = n0 + wn * 64 + ni * 16 + (lane & 15);
                C[(size_t)rr * N + cc] = acc[mi][ni][rg];
            }
}

extern "C" void kernel_launch(void* const* d_in, const int* in_sizes, int n_in,
                              void* d_out, int out_size, void* d_ws, size_t ws_size,
                              hipStream_t stream) {
    const float* x     = (const float*)d_in[0];   // [8192][3072] f32
    const float* V     = (const float*)d_in[1];   // [3072][3072] f32
    const float* alpha = (const float*)d_in[2];   // [3072] f32
    float* out = (float*)d_out;                   // [8192][3072] f32

    // ws layout: a[3072] f32 | x_bf16 [8192*3072] | W_bf16 [3072*3072]
    float* a_ws = (float*)d_ws;
    unsigned short* xb = (unsigned short*)((char*)d_ws + 16384);
    unsigned short* Wb = (unsigned short*)((char*)d_ws + 16384 + (size_t)BATCHN * NDIM * 2);

    hipLaunchKernelGGL(dykstra_kernel, dim3(1), dim3(64), 0, stream, alpha, a_ws);
    hipLaunchKernelGGL(build_w, dim3(NDIM / 64, NDIM / 64), dim3(256), 0, stream, V, a_ws, Wb);
    hipLaunchKernelGGL(convert_x, dim3(2048), dim3(256), 0, stream, x, xb, BATCHN * NDIM);
    hipLaunchKernelGGL(gemm_bt, dim3((BATCHN / BM) * (NDIM / BN)), dim3(256), 0, stream,
                       xb, Wb, out, BATCHN, NDIM, NDIM, NDIM / BN);
}